// Round 1
// baseline (446.881 us; speedup 1.0000x reference)
//
#include <hip/hip_runtime.h>

typedef __bf16 bf16x8 __attribute__((ext_vector_type(8)));
typedef float f32x4 __attribute__((ext_vector_type(4)));

#define D_MODEL 768
#define NH 12
#define DKH 64
#define BATCH 4
#define SEQ 2048
#define ROWS (BATCH*SEQ)   /* 8192 */
#define N_QKV (3*D_MODEL)  /* 2304 */

// ---------------- convert fp32 -> bf16 ----------------
__global__ void k_convert(const float* __restrict__ in, __bf16* __restrict__ out, int n) {
  int i = (blockIdx.x * blockDim.x + threadIdx.x) * 4;
  if (i >= n) return;
  float4 v = *(const float4*)(in + i);
  out[i+0] = (__bf16)v.x; out[i+1] = (__bf16)v.y;
  out[i+2] = (__bf16)v.z; out[i+3] = (__bf16)v.w;
}

// ---------------- transpose fp32 [R][C] -> bf16 [C][R] ----------------
__global__ void k_transpose(const float* __restrict__ in, __bf16* __restrict__ out, int R, int C) {
  __shared__ float tile[32][33];
  int c0 = blockIdx.x * 32, r0 = blockIdx.y * 32;
  int tx = threadIdx.x, ty = threadIdx.y;   // (32, 8)
  #pragma unroll
  for (int i = 0; i < 4; ++i) {
    int r = ty + i*8;
    tile[r][tx] = in[(size_t)(r0 + r)*C + c0 + tx];
  }
  __syncthreads();
  #pragma unroll
  for (int i = 0; i < 4; ++i) {
    int c = ty + i*8;
    out[(size_t)(c0 + c)*R + r0 + tx] = (__bf16)tile[tx][c];
  }
}

// ---------------- GEMM core: C[128x128] tile, A[M][K] bf16, Bt[N][K] bf16 ----------------
// 256 threads = 4 waves in 2x2 grid, each wave 64x64 (4x4 frags of 16x16x32).
__device__ __forceinline__ void gemm_core(const __bf16* __restrict__ A, int lda,
                                          const __bf16* __restrict__ Bt, int ldb,
                                          int K, int m0, int n0,
                                          __bf16* lA, __bf16* lB, f32x4 acc[4][4]) {
  const int tid  = threadIdx.x;
  const int lane = tid & 63;
  const int wid  = tid >> 6;
  const int wm   = (wid >> 1) * 64;
  const int wn   = (wid & 1) * 64;
  const int lr   = lane & 15;
  const int lk   = lane >> 4;

  for (int kt = 0; kt < K; kt += 32) {
    // stage A/B tiles [128][32] bf16 (8KB each) via global_load_lds width=16
    #pragma unroll
    for (int c = 0; c < 2; ++c) {
      int chunk = wid*2 + c;               // 0..7
      int bo = chunk*1024 + lane*16;       // byte offset in tile
      int m  = bo >> 6;                    // 64B per row
      int kb = (bo & 63) >> 1;             // element in row
      __builtin_amdgcn_global_load_lds(
        (const __attribute__((address_space(1))) void*)(A + (size_t)(m0 + m)*lda + kt + kb),
        (__attribute__((address_space(3))) void*)(lA + chunk*512), 16, 0, 0);
      __builtin_amdgcn_global_load_lds(
        (const __attribute__((address_space(1))) void*)(Bt + (size_t)(n0 + m)*ldb + kt + kb),
        (__attribute__((address_space(3))) void*)(lB + chunk*512), 16, 0, 0);
    }
    __syncthreads();
    bf16x8 af[4], bfr[4];
    #pragma unroll
    for (int i = 0; i < 4; ++i) {
      af[i]  = *(const bf16x8*)(lA + (wm + i*16 + lr)*32 + lk*8);
      bfr[i] = *(const bf16x8*)(lB + (wn + i*16 + lr)*32 + lk*8);
    }
    #pragma unroll
    for (int mi = 0; mi < 4; ++mi)
      #pragma unroll
      for (int ni = 0; ni < 4; ++ni)
        acc[mi][ni] = __builtin_amdgcn_mfma_f32_16x16x32_bf16(af[mi], bfr[ni], acc[mi][ni], 0, 0, 0);
    __syncthreads();
  }
}

// ---------------- GEMM1: qkv = xb @ WqkvT + bqkv, scatter to Q,K,V^T ----------------
__global__ __launch_bounds__(256) void k_gemm_qkv(const __bf16* __restrict__ xb,
                                                  const __bf16* __restrict__ wT,
                                                  const float* __restrict__ bias,
                                                  __bf16* __restrict__ qb,
                                                  __bf16* __restrict__ kb,
                                                  __bf16* __restrict__ vtb) {
  __shared__ __align__(16) __bf16 lA[128*32];
  __shared__ __align__(16) __bf16 lB[128*32];
  f32x4 acc[4][4];
  #pragma unroll
  for (int i = 0; i < 4; ++i)
    #pragma unroll
    for (int j = 0; j < 4; ++j) { f32x4 z = {0.f,0.f,0.f,0.f}; acc[i][j] = z; }

  const int m0 = blockIdx.y * 128, n0 = blockIdx.x * 128;
  gemm_core(xb, D_MODEL, wT, D_MODEL, D_MODEL, m0, n0, lA, lB, acc);

  const int lane = threadIdx.x & 63;
  const int wid  = threadIdx.x >> 6;
  const int wm = (wid >> 1) * 64, wn = (wid & 1) * 64;
  const int lr = lane & 15, lk = lane >> 4;
  #pragma unroll
  for (int mi = 0; mi < 4; ++mi) {
    #pragma unroll
    for (int ni = 0; ni < 4; ++ni) {
      int col = n0 + wn + ni*16 + lr;
      int t   = col / D_MODEL;
      int r2  = col - t*D_MODEL;
      int hh  = r2 >> 6, dk = r2 & 63;
      float bv = bias[col];
      #pragma unroll
      for (int j = 0; j < 4; ++j) {
        int row = m0 + wm + mi*16 + lk*4 + j;
        int bb = row >> 11, ss = row & 2047;
        __bf16 v = (__bf16)(acc[mi][ni][j] + bv);
        if (t == 0)      qb [(((size_t)bb*NH + hh)*SEQ + ss)*DKH + dk] = v;
        else if (t == 1) kb [(((size_t)bb*NH + hh)*SEQ + ss)*DKH + dk] = v;
        else             vtb[(((size_t)bb*NH + hh)*DKH + dk)*SEQ + ss] = v;
      }
    }
  }
}

// ---------------- GEMM3: out = attn @ WoutT + bout (fp32 out) ----------------
__global__ __launch_bounds__(256) void k_gemm_out(const __bf16* __restrict__ ab,
                                                  const __bf16* __restrict__ wT,
                                                  const float* __restrict__ bias,
                                                  float* __restrict__ out) {
  __shared__ __align__(16) __bf16 lA[128*32];
  __shared__ __align__(16) __bf16 lB[128*32];
  f32x4 acc[4][4];
  #pragma unroll
  for (int i = 0; i < 4; ++i)
    #pragma unroll
    for (int j = 0; j < 4; ++j) { f32x4 z = {0.f,0.f,0.f,0.f}; acc[i][j] = z; }

  const int m0 = blockIdx.y * 128, n0 = blockIdx.x * 128;
  gemm_core(ab, D_MODEL, wT, D_MODEL, D_MODEL, m0, n0, lA, lB, acc);

  const int lane = threadIdx.x & 63;
  const int wid  = threadIdx.x >> 6;
  const int wm = (wid >> 1) * 64, wn = (wid & 1) * 64;
  const int lr = lane & 15, lk = lane >> 4;
  #pragma unroll
  for (int mi = 0; mi < 4; ++mi) {
    #pragma unroll
    for (int ni = 0; ni < 4; ++ni) {
      int col = n0 + wn + ni*16 + lr;
      float bv = bias[col];
      #pragma unroll
      for (int j = 0; j < 4; ++j) {
        int row = m0 + wm + mi*16 + lk*4 + j;
        out[(size_t)row*D_MODEL + col] = acc[mi][ni][j] + bv;
      }
    }
  }
}

// ---------------- Flash attention (causal), bf16 MFMA ----------------
// grid (SEQ/64, B*NH), 256 threads = 4 waves; each wave owns 16 q-rows.
__global__ __launch_bounds__(256) void k_attn(const __bf16* __restrict__ q,
                                              const __bf16* __restrict__ k,
                                              const __bf16* __restrict__ vt,
                                              __bf16* __restrict__ out) {
  __shared__ __align__(16) __bf16 pbuf[4][16*32];
  const int lane = threadIdx.x & 63;
  const int wid  = threadIdx.x >> 6;
  const int bh = blockIdx.y;
  const int b = bh / NH, h = bh - b*NH;
  const int q0 = blockIdx.x*64 + wid*16;
  const int lr = lane & 15, lk = lane >> 4;

  const __bf16* qh = q  + (size_t)bh*SEQ*DKH;
  const __bf16* kh = k  + (size_t)bh*SEQ*DKH;
  const __bf16* vh = vt + (size_t)bh*DKH*SEQ;
  __bf16* pw = pbuf[wid];

  bf16x8 aq[2];
  aq[0] = *(const bf16x8*)(qh + (q0 + lr)*DKH + lk*8);
  aq[1] = *(const bf16x8*)(qh + (q0 + lr)*DKH + 32 + lk*8);

  f32x4 o[4];
  #pragma unroll
  for (int i = 0; i < 4; ++i) { f32x4 z = {0.f,0.f,0.f,0.f}; o[i] = z; }
  float m_i[4] = {-1e30f, -1e30f, -1e30f, -1e30f};
  float l_i[4] = {0.f, 0.f, 0.f, 0.f};

  const int kv_end = q0 + 16;   // causal: kv <= q_row, max q_row = q0+15
  for (int kv0 = 0; kv0 < kv_end; kv0 += 32) {
    // ---- S = Q K^T (16 x 32) ----
    f32x4 sc[2];
    #pragma unroll
    for (int n = 0; n < 2; ++n) { f32x4 z = {0.f,0.f,0.f,0.f}; sc[n] = z; }
    #pragma unroll
    for (int n = 0; n < 2; ++n)
      #pragma unroll
      for (int kf = 0; kf < 2; ++kf) {
        bf16x8 bk = *(const bf16x8*)(kh + (kv0 + n*16 + lr)*DKH + kf*32 + lk*8);
        sc[n] = __builtin_amdgcn_mfma_f32_16x16x32_bf16(aq[kf], bk, sc[n], 0, 0, 0);
      }
    // ---- scale + causal mask ----
    float s[2][4];
    #pragma unroll
    for (int n = 0; n < 2; ++n) {
      int kv = kv0 + n*16 + lr;
      #pragma unroll
      for (int j = 0; j < 4; ++j) {
        int qr = q0 + lk*4 + j;
        float v = sc[n][j] * 0.125f;
        s[n][j] = (kv > qr) ? -1e30f : v;
      }
    }
    // ---- row max (reduce over 16 lanes holding the 16 cols) ----
    float pm[4];
    #pragma unroll
    for (int j = 0; j < 4; ++j) {
      pm[j] = fmaxf(s[0][j], s[1][j]);
      #pragma unroll
      for (int msk = 1; msk <= 8; msk <<= 1)
        pm[j] = fmaxf(pm[j], __shfl_xor(pm[j], msk));
    }
    float alpha[4];
    #pragma unroll
    for (int j = 0; j < 4; ++j) {
      float mn = fmaxf(m_i[j], pm[j]);
      alpha[j] = __expf(m_i[j] - mn);
      m_i[j] = mn;
    }
    // ---- P = exp(s - m), row sums, store bf16 P to LDS ----
    float rs[4] = {0.f, 0.f, 0.f, 0.f};
    #pragma unroll
    for (int n = 0; n < 2; ++n)
      #pragma unroll
      for (int j = 0; j < 4; ++j) {
        __bf16 p = (__bf16)__expf(s[n][j] - m_i[j]);
        rs[j] += (float)p;
        pw[(lk*4 + j)*32 + n*16 + lr] = p;
      }
    #pragma unroll
    for (int j = 0; j < 4; ++j) {
      #pragma unroll
      for (int msk = 1; msk <= 8; msk <<= 1)
        rs[j] += __shfl_xor(rs[j], msk);
      l_i[j] = l_i[j]*alpha[j] + rs[j];
    }
    // ---- O = O*alpha + P V ----
    bf16x8 pa = *(const bf16x8*)(pw + lr*32 + lk*8);
    #pragma unroll
    for (int df = 0; df < 4; ++df) {
      #pragma unroll
      for (int j = 0; j < 4; ++j) o[df][j] *= alpha[j];
      bf16x8 bv = *(const bf16x8*)(vh + (df*16 + lr)*SEQ + kv0 + lk*8);
      o[df] = __builtin_amdgcn_mfma_f32_16x16x32_bf16(pa, bv, o[df], 0, 0, 0);
    }
  }
  // ---- epilogue: O/l, write [B][S][H*DK] bf16 ----
  #pragma unroll
  for (int j = 0; j < 4; ++j) l_i[j] = 1.0f / l_i[j];
  #pragma unroll
  for (int df = 0; df < 4; ++df) {
    int d = df*16 + lr;
    #pragma unroll
    for (int j = 0; j < 4; ++j) {
      int ss = q0 + lk*4 + j;
      out[((size_t)b*SEQ + ss)*D_MODEL + h*DKH + d] = (__bf16)(o[df][j] * l_i[j]);
    }
  }
}

// ---------------- launch ----------------
extern "C" void kernel_launch(void* const* d_in, const int* in_sizes, int n_in,
                              void* d_out, int out_size, void* d_ws, size_t ws_size,
                              hipStream_t stream) {
  const float* x    = (const float*)d_in[0];
  /* d_in[1] = causal mask, implemented analytically */
  const float* Wqkv = (const float*)d_in[2];
  const float* bqkv = (const float*)d_in[3];
  const float* Wout = (const float*)d_in[4];
  const float* bout = (const float*)d_in[5];
  float* out = (float*)d_out;

  char* w = (char*)d_ws;
  __bf16* xb    = (__bf16*)w; w += (size_t)ROWS*D_MODEL*2;
  __bf16* wqkvT = (__bf16*)w; w += (size_t)N_QKV*D_MODEL*2;
  __bf16* woutT = (__bf16*)w; w += (size_t)D_MODEL*D_MODEL*2;
  __bf16* qb    = (__bf16*)w; w += (size_t)BATCH*NH*SEQ*DKH*2;
  __bf16* kb    = (__bf16*)w; w += (size_t)BATCH*NH*SEQ*DKH*2;
  __bf16* vtb   = (__bf16*)w; w += (size_t)BATCH*NH*SEQ*DKH*2;
  __bf16* attnb = (__bf16*)w; w += (size_t)ROWS*D_MODEL*2;

  k_convert<<<(ROWS*D_MODEL/4 + 255)/256, 256, 0, stream>>>(x, xb, ROWS*D_MODEL);
  k_transpose<<<dim3(N_QKV/32, D_MODEL/32), dim3(32, 8), 0, stream>>>(Wqkv, wqkvT, D_MODEL, N_QKV);
  k_transpose<<<dim3(D_MODEL/32, D_MODEL/32), dim3(32, 8), 0, stream>>>(Wout, woutT, D_MODEL, D_MODEL);
  k_gemm_qkv<<<dim3(N_QKV/128, ROWS/128), 256, 0, stream>>>(xb, wqkvT, bqkv, qb, kb, vtb);
  k_attn<<<dim3(SEQ/64, BATCH*NH), 256, 0, stream>>>(qb, kb, vtb, attnb);
  k_gemm_out<<<dim3(D_MODEL/128, ROWS/128), 256, 0, stream>>>(attnb, woutT, bout, out);
}

// Round 2
// 255.205 us; speedup vs baseline: 1.7511x; 1.7511x over previous
//
#include <hip/hip_runtime.h>

typedef __bf16 bf16x8 __attribute__((ext_vector_type(8)));
typedef float f32x4 __attribute__((ext_vector_type(4)));

#define D_MODEL 768
#define NH 12
#define DKH 64
#define BATCH 4
#define SEQ 2048
#define ROWS (BATCH*SEQ)   /* 8192 */
#define N_QKV (3*D_MODEL)  /* 2304 */

// ---------------- convert fp32 -> bf16 ----------------
__global__ void k_convert(const float* __restrict__ in, __bf16* __restrict__ out, int n) {
  int i = (blockIdx.x * blockDim.x + threadIdx.x) * 4;
  if (i >= n) return;
  float4 v = *(const float4*)(in + i);
  out[i+0] = (__bf16)v.x; out[i+1] = (__bf16)v.y;
  out[i+2] = (__bf16)v.z; out[i+3] = (__bf16)v.w;
}

// ---------------- transpose fp32 [R][C] -> bf16 [C][R] ----------------
__global__ void k_transpose(const float* __restrict__ in, __bf16* __restrict__ out, int R, int C) {
  __shared__ float tile[32][33];
  int c0 = blockIdx.x * 32, r0 = blockIdx.y * 32;
  int tx = threadIdx.x, ty = threadIdx.y;   // (32, 8)
  #pragma unroll
  for (int i = 0; i < 4; ++i) {
    int r = ty + i*8;
    tile[r][tx] = in[(size_t)(r0 + r)*C + c0 + tx];
  }
  __syncthreads();
  #pragma unroll
  for (int i = 0; i < 4; ++i) {
    int c = ty + i*8;
    out[(size_t)(c0 + c)*R + r0 + tx] = (__bf16)tile[tx][c];
  }
}

// ---------------- GEMM core: C[128x128] tile, A[M][K] bf16, Bt[N][K] bf16 ----------------
__device__ __forceinline__ void gemm_core(const __bf16* __restrict__ A, int lda,
                                          const __bf16* __restrict__ Bt, int ldb,
                                          int K, int m0, int n0,
                                          __bf16* lA, __bf16* lB, f32x4 acc[4][4]) {
  const int tid  = threadIdx.x;
  const int lane = tid & 63;
  const int wid  = tid >> 6;
  const int wm   = (wid >> 1) * 64;
  const int wn   = (wid & 1) * 64;
  const int lr   = lane & 15;
  const int lk   = lane >> 4;

  for (int kt = 0; kt < K; kt += 32) {
    #pragma unroll
    for (int c = 0; c < 2; ++c) {
      int chunk = wid*2 + c;               // 0..7
      int bo = chunk*1024 + lane*16;       // byte offset in tile
      int m  = bo >> 6;                    // 64B per row
      int kb = (bo & 63) >> 1;             // element in row
      __builtin_amdgcn_global_load_lds(
        (const __attribute__((address_space(1))) void*)(A + (size_t)(m0 + m)*lda + kt + kb),
        (__attribute__((address_space(3))) void*)(lA + chunk*512), 16, 0, 0);
      __builtin_amdgcn_global_load_lds(
        (const __attribute__((address_space(1))) void*)(Bt + (size_t)(n0 + m)*ldb + kt + kb),
        (__attribute__((address_space(3))) void*)(lB + chunk*512), 16, 0, 0);
    }
    __syncthreads();
    bf16x8 af[4], bfr[4];
    #pragma unroll
    for (int i = 0; i < 4; ++i) {
      af[i]  = *(const bf16x8*)(lA + (wm + i*16 + lr)*32 + lk*8);
      bfr[i] = *(const bf16x8*)(lB + (wn + i*16 + lr)*32 + lk*8);
    }
    #pragma unroll
    for (int mi = 0; mi < 4; ++mi)
      #pragma unroll
      for (int ni = 0; ni < 4; ++ni)
        acc[mi][ni] = __builtin_amdgcn_mfma_f32_16x16x32_bf16(af[mi], bfr[ni], acc[mi][ni], 0, 0, 0);
    __syncthreads();
  }
}

// ---------------- GEMM1: qkv = xb @ WqkvT + bqkv, scatter to Q,K,V^T ----------------
__global__ __launch_bounds__(256) void k_gemm_qkv(const __bf16* __restrict__ xb,
                                                  const __bf16* __restrict__ wT,
                                                  const float* __restrict__ bias,
                                                  __bf16* __restrict__ qb,
                                                  __bf16* __restrict__ kb,
                                                  __bf16* __restrict__ vtb) {
  __shared__ __align__(16) __bf16 lA[128*32];
  __shared__ __align__(16) __bf16 lB[128*32];
  f32x4 acc[4][4];
  #pragma unroll
  for (int i = 0; i < 4; ++i)
    #pragma unroll
    for (int j = 0; j < 4; ++j) { f32x4 z = {0.f,0.f,0.f,0.f}; acc[i][j] = z; }

  const int m0 = blockIdx.y * 128, n0 = blockIdx.x * 128;
  gemm_core(xb, D_MODEL, wT, D_MODEL, D_MODEL, m0, n0, lA, lB, acc);

  const int lane = threadIdx.x & 63;
  const int wid  = threadIdx.x >> 6;
  const int wm = (wid >> 1) * 64, wn = (wid & 1) * 64;
  const int lr = lane & 15, lk = lane >> 4;
  #pragma unroll
  for (int mi = 0; mi < 4; ++mi) {
    #pragma unroll
    for (int ni = 0; ni < 4; ++ni) {
      int col = n0 + wn + ni*16 + lr;
      int t   = col / D_MODEL;
      int r2  = col - t*D_MODEL;
      int hh  = r2 >> 6, dk = r2 & 63;
      float bv = bias[col];
      #pragma unroll
      for (int j = 0; j < 4; ++j) {
        int row = m0 + wm + mi*16 + lk*4 + j;
        int bb = row >> 11, ss = row & 2047;
        __bf16 v = (__bf16)(acc[mi][ni][j] + bv);
        if (t == 0)      qb [(((size_t)bb*NH + hh)*SEQ + ss)*DKH + dk] = v;
        else if (t == 1) kb [(((size_t)bb*NH + hh)*SEQ + ss)*DKH + dk] = v;
        else             vtb[(((size_t)bb*NH + hh)*DKH + dk)*SEQ + ss] = v;
      }
    }
  }
}

// ---------------- GEMM3: out = attn @ WoutT + bout (fp32 out) ----------------
__global__ __launch_bounds__(256) void k_gemm_out(const __bf16* __restrict__ ab,
                                                  const __bf16* __restrict__ wT,
                                                  const float* __restrict__ bias,
                                                  float* __restrict__ out) {
  __shared__ __align__(16) __bf16 lA[128*32];
  __shared__ __align__(16) __bf16 lB[128*32];
  f32x4 acc[4][4];
  #pragma unroll
  for (int i = 0; i < 4; ++i)
    #pragma unroll
    for (int j = 0; j < 4; ++j) { f32x4 z = {0.f,0.f,0.f,0.f}; acc[i][j] = z; }

  const int m0 = blockIdx.y * 128, n0 = blockIdx.x * 128;
  gemm_core(ab, D_MODEL, wT, D_MODEL, D_MODEL, m0, n0, lA, lB, acc);

  const int lane = threadIdx.x & 63;
  const int wid  = threadIdx.x >> 6;
  const int wm = (wid >> 1) * 64, wn = (wid & 1) * 64;
  const int lr = lane & 15, lk = lane >> 4;
  #pragma unroll
  for (int mi = 0; mi < 4; ++mi) {
    #pragma unroll
    for (int ni = 0; ni < 4; ++ni) {
      int col = n0 + wn + ni*16 + lr;
      float bv = bias[col];
      #pragma unroll
      for (int j = 0; j < 4; ++j) {
        int row = m0 + wm + mi*16 + lk*4 + j;
        out[(size_t)row*D_MODEL + col] = acc[mi][ni][j] + bv;
      }
    }
  }
}

// ---------------- Flash attention (causal) ----------------
// grid (16, B*NH), 256 thr = 4 waves; block owns 128 q-rows (wave: 32), KVBLK=64.
// K/V^T tiles double-buffered in LDS via global_load_lds, XOR-swizzled
// (pre-swizzled global source, swizzled reads -- rule both-sides-or-neither).
__global__ __launch_bounds__(256) void k_attn(const __bf16* __restrict__ q,
                                              const __bf16* __restrict__ k,
                                              const __bf16* __restrict__ vt,
                                              __bf16* __restrict__ out) {
  __shared__ __align__(16) char lsK[2][8192];   // [64 kv][64 d] bf16, swizzled rows
  __shared__ __align__(16) char lsV[2][8192];   // [64 d][64 kv] bf16, swizzled rows
  __shared__ __align__(16) char lsP[4][4096];   // per-wave P [32 q][64 kv] bf16, swizzled

  const int tid  = threadIdx.x;
  const int lane = tid & 63;
  const int wid  = tid >> 6;
  const int lr   = lane & 15;
  const int lk   = lane >> 4;

  const int bh = blockIdx.y;
  const int b  = bh / NH, h = bh - b*NH;
  // spread tile sizes across co-resident blocks (causal load balance)
  const int qi  = (blockIdx.x + 5*(blockIdx.y >> 4)) & 15;
  const int qb0 = qi * 128;
  const int q0w = qb0 + wid * 32;

  const __bf16* qh = q + (size_t)bh*SEQ*DKH;
  const char*   kB = (const char*)(k  + (size_t)bh*SEQ*DKH);
  const char*   vB = (const char*)(vt + (size_t)bh*DKH*SEQ);
  char* pw = lsP[wid];

  // Q fragments in registers: rows q0w + r*16 + lr, k-bytes kh*64 + lk*16
  bf16x8 aq[2][2];
  #pragma unroll
  for (int r = 0; r < 2; ++r)
    #pragma unroll
    for (int kh2 = 0; kh2 < 2; ++kh2)
      aq[r][kh2] = *(const bf16x8*)(qh + (size_t)(q0w + r*16 + lr)*DKH + kh2*32 + lk*8);

  f32x4 o[2][4];
  #pragma unroll
  for (int r = 0; r < 2; ++r)
    #pragma unroll
    for (int df = 0; df < 4; ++df) { f32x4 z = {0.f,0.f,0.f,0.f}; o[r][df] = z; }
  float m_i[2][4], l_i[2][4];
  #pragma unroll
  for (int r = 0; r < 2; ++r)
    #pragma unroll
    for (int j = 0; j < 4; ++j) { m_i[r][j] = -1e30f; l_i[r][j] = 0.f; }

  const int nt = qb0/64 + 2;   // kv tiles: [0, qb0+128)

  auto stage = [&](int buf, int kv0) {
    #pragma unroll
    for (int c = 0; c < 2; ++c) {
      int chunk = wid*2 + c;                 // 0..7, 1024B each
      int lb    = chunk*1024 + lane*16;      // linear dest byte in tile
      int row   = lb >> 7;                   // 128B rows
      int colb  = (lb & 127) ^ ((row & 7) << 4);  // pre-swizzled source column
      __builtin_amdgcn_global_load_lds(
        (const __attribute__((address_space(1))) void*)(kB + (size_t)(kv0 + row)*128 + colb),
        (__attribute__((address_space(3))) void*)(lsK[buf] + chunk*1024), 16, 0, 0);
      __builtin_amdgcn_global_load_lds(
        (const __attribute__((address_space(1))) void*)(vB + (size_t)row*(SEQ*2) + (size_t)kv0*2 + colb),
        (__attribute__((address_space(3))) void*)(lsV[buf] + chunk*1024), 16, 0, 0);
    }
  };

  stage(0, 0);
  __syncthreads();
  int cur = 0;

  for (int t = 0; t < nt; ++t) {
    const int kv0 = t * 64;
    if (t + 1 < nt) stage(cur ^ 1, kv0 + 64);

    if (kv0 <= q0w + 31) {          // wave-uniform causal activity
      // ---- S = Q K^T : [32 q][64 kv] ----
      f32x4 sc[2][4];
      #pragma unroll
      for (int r = 0; r < 2; ++r)
        #pragma unroll
        for (int n = 0; n < 4; ++n) { f32x4 z = {0.f,0.f,0.f,0.f}; sc[r][n] = z; }
      #pragma unroll
      for (int n = 0; n < 4; ++n) {
        int kvl = n*16 + lr;
        const char* kr = lsK[cur] + kvl*128;
        int sw = (kvl & 7) << 4;
        bf16x8 bk0 = *(const bf16x8*)(kr + ((lk*16) ^ sw));
        bf16x8 bk1 = *(const bf16x8*)(kr + ((64 + lk*16) ^ sw));
        #pragma unroll
        for (int r = 0; r < 2; ++r) {
          sc[r][n] = __builtin_amdgcn_mfma_f32_16x16x32_bf16(aq[r][0], bk0, sc[r][n], 0, 0, 0);
          sc[r][n] = __builtin_amdgcn_mfma_f32_16x16x32_bf16(aq[r][1], bk1, sc[r][n], 0, 0, 0);
        }
      }
      // ---- scale + causal mask (in place) ----
      const bool diag = (kv0 + 63 > q0w);
      #pragma unroll
      for (int r = 0; r < 2; ++r)
        #pragma unroll
        for (int n = 0; n < 4; ++n) {
          int kv = kv0 + n*16 + lr;
          #pragma unroll
          for (int j = 0; j < 4; ++j) {
            float v = sc[r][n][j] * 0.125f;
            if (diag && kv > q0w + r*16 + lk*4 + j) v = -1e30f;
            sc[r][n][j] = v;
          }
        }
      // ---- online softmax: row max, alpha ----
      float alpha[2][4];
      #pragma unroll
      for (int r = 0; r < 2; ++r)
        #pragma unroll
        for (int j = 0; j < 4; ++j) {
          float pm = fmaxf(fmaxf(sc[r][0][j], sc[r][1][j]), fmaxf(sc[r][2][j], sc[r][3][j]));
          #pragma unroll
          for (int msk = 1; msk <= 8; msk <<= 1)
            pm = fmaxf(pm, __shfl_xor(pm, msk));
          float mn = fmaxf(m_i[r][j], pm);
          alpha[r][j] = __expf(m_i[r][j] - mn);
          m_i[r][j] = mn;
        }
      // ---- P = exp(s-m) -> bf16 -> LDS (swizzled), row sums ----
      float rs[2][4] = {{0.f,0.f,0.f,0.f},{0.f,0.f,0.f,0.f}};
      #pragma unroll
      for (int r = 0; r < 2; ++r)
        #pragma unroll
        for (int n = 0; n < 4; ++n)
          #pragma unroll
          for (int j = 0; j < 4; ++j) {
            int row = r*16 + lk*4 + j;
            __bf16 pb = (__bf16)__expf(sc[r][n][j] - m_i[r][j]);
            rs[r][j] += (float)pb;
            *(__bf16*)(pw + row*128 + ((2*(n*16 + lr)) ^ ((row & 7) << 4))) = pb;
          }
      #pragma unroll
      for (int r = 0; r < 2; ++r)
        #pragma unroll
        for (int j = 0; j < 4; ++j) {
          float v = rs[r][j];
          #pragma unroll
          for (int msk = 1; msk <= 8; msk <<= 1) v += __shfl_xor(v, msk);
          l_i[r][j] = l_i[r][j] * alpha[r][j] + v;
        }
      // ---- O = O*alpha + P V ----
      #pragma unroll
      for (int r = 0; r < 2; ++r)
        #pragma unroll
        for (int df = 0; df < 4; ++df)
          #pragma unroll
          for (int j = 0; j < 4; ++j)
            o[r][df][j] *= alpha[r][j];
      bf16x8 pa[2][2];
      #pragma unroll
      for (int r = 0; r < 2; ++r) {
        int row = r*16 + lr;
        int sw = (row & 7) << 4;
        #pragma unroll
        for (int kh2 = 0; kh2 < 2; ++kh2)
          pa[r][kh2] = *(const bf16x8*)(pw + row*128 + ((kh2*64 + lk*16) ^ sw));
      }
      #pragma unroll
      for (int df = 0; df < 4; ++df) {
        int d = df*16 + lr;
        const char* vr = lsV[cur] + d*128;
        int sw = (d & 7) << 4;
        bf16x8 bv0 = *(const bf16x8*)(vr + ((lk*16) ^ sw));
        bf16x8 bv1 = *(const bf16x8*)(vr + ((64 + lk*16) ^ sw));
        #pragma unroll
        for (int r = 0; r < 2; ++r) {
          o[r][df] = __builtin_amdgcn_mfma_f32_16x16x32_bf16(pa[r][0], bv0, o[r][df], 0, 0, 0);
          o[r][df] = __builtin_amdgcn_mfma_f32_16x16x32_bf16(pa[r][1], bv1, o[r][df], 0, 0, 0);
        }
      }
    }
    __syncthreads();
    cur ^= 1;
  }

  // ---- epilogue: O/l -> [B][S][D_MODEL] bf16 ----
  float inv[2][4];
  #pragma unroll
  for (int r = 0; r < 2; ++r)
    #pragma unroll
    for (int j = 0; j < 4; ++j) inv[r][j] = 1.0f / l_i[r][j];
  #pragma unroll
  for (int r = 0; r < 2; ++r)
    #pragma unroll
    for (int df = 0; df < 4; ++df) {
      int d = df*16 + lr;
      #pragma unroll
      for (int j = 0; j < 4; ++j) {
        int ss = q0w + r*16 + lk*4 + j;
        out[((size_t)b*SEQ + ss)*D_MODEL + h*DKH + d] = (__bf16)(o[r][df][j] * inv[r][j]);
      }
    }
}

// ---------------- launch ----------------
extern "C" void kernel_launch(void* const* d_in, const int* in_sizes, int n_in,
                              void* d_out, int out_size, void* d_ws, size_t ws_size,
                              hipStream_t stream) {
  const float* x    = (const float*)d_in[0];
  /* d_in[1] = causal mask, implemented analytically */
  const float* Wqkv = (const float*)d_in[2];
  const float* bqkv = (const float*)d_in[3];
  const float* Wout = (const float*)d_in[4];
  const float* bout = (const float*)d_in[5];
  float* out = (float*)d_out;

  char* w = (char*)d_ws;
  __bf16* xb    = (__bf16*)w; w += (size_t)ROWS*D_MODEL*2;
  __bf16* wqkvT = (__bf16*)w; w += (size_t)N_QKV*D_MODEL*2;
  __bf16* woutT = (__bf16*)w; w += (size_t)D_MODEL*D_MODEL*2;
  __bf16* qb    = (__bf16*)w; w += (size_t)BATCH*NH*SEQ*DKH*2;
  __bf16* kb    = (__bf16*)w; w += (size_t)BATCH*NH*SEQ*DKH*2;
  __bf16* vtb   = (__bf16*)w; w += (size_t)BATCH*NH*SEQ*DKH*2;
  __bf16* attnb = (__bf16*)w; w += (size_t)ROWS*D_MODEL*2;

  k_convert<<<(ROWS*D_MODEL/4 + 255)/256, 256, 0, stream>>>(x, xb, ROWS*D_MODEL);
  k_transpose<<<dim3(N_QKV/32, D_MODEL/32), dim3(32, 8), 0, stream>>>(Wqkv, wqkvT, D_MODEL, N_QKV);
  k_transpose<<<dim3(D_MODEL/32, D_MODEL/32), dim3(32, 8), 0, stream>>>(Wout, woutT, D_MODEL, D_MODEL);
  k_gemm_qkv<<<dim3(N_QKV/128, ROWS/128), 256, 0, stream>>>(xb, wqkvT, bqkv, qb, kb, vtb);
  k_attn<<<dim3(16, BATCH*NH), 256, 0, stream>>>(qb, kb, vtb, attnb);
  k_gemm_out<<<dim3(D_MODEL/128, ROWS/128), 256, 0, stream>>>(attnb, woutT, bout, out);
}